// Round 1
// baseline (614.043 us; speedup 1.0000x reference)
//
#include <hip/hip_runtime.h>
#include <hip/hip_bf16.h>
#include <stdint.h>

#define AS1 __attribute__((address_space(1)))
#define AS3 __attribute__((address_space(3)))

typedef __attribute__((ext_vector_type(8))) short short8;
typedef __attribute__((ext_vector_type(4))) float floatx4;

__device__ __forceinline__ unsigned short f2b_rne(float f) {
  union { float f; unsigned u; } c; c.f = f;
  unsigned u = c.u;
  unsigned r = u + 0x7fffu + ((u >> 16) & 1u);
  return (unsigned short)(r >> 16);
}

// ---------------------------------------------------------------------------
// Weight prep: Wt[n][k] = bf16(W_seg[k][c])  (B^T layout, K contiguous)
// rows 0..255=W_val, 256..511=W_so, 512..767=W_tso, 768..895=W_aw, 896..1023=W_taw
// bcat[n] = concatenated biases in same order.
// ---------------------------------------------------------------------------
__global__ void prep_weights(const float* __restrict__ Wv,  const float* __restrict__ bv,
                             const float* __restrict__ Wso, const float* __restrict__ bso,
                             const float* __restrict__ Waw, const float* __restrict__ baw,
                             const float* __restrict__ Wtso,const float* __restrict__ btso,
                             const float* __restrict__ Wtaw,const float* __restrict__ btaw,
                             unsigned short* __restrict__ Wt, float* __restrict__ bcat) {
  int n = blockIdx.x;   // 0..1023
  int k = threadIdx.x;  // 0..255
  const float* W; const float* b; int c, N;
  if (n < 256)      { W = Wv;   b = bv;   c = n;       N = 256; }
  else if (n < 512) { W = Wso;  b = bso;  c = n - 256; N = 256; }
  else if (n < 768) { W = Wtso; b = btso; c = n - 512; N = 256; }
  else if (n < 896) { W = Waw;  b = baw;  c = n - 768; N = 128; }
  else              { W = Wtaw; b = btaw; c = n - 896; N = 128; }
  Wt[n * 256 + k] = f2b_rne(W[(size_t)k * N + c]);
  if (k == 0) bcat[n] = b[c];
}

// ---------------------------------------------------------------------------
// Main GEMM: C[m, n] for n-tiles 0..5 (val x2, so x2, tso x2), 128x128 tile.
// A (fp32) converted to bf16 during LDS staging; B staged via global_load_lds.
// ---------------------------------------------------------------------------
__global__ __launch_bounds__(256, 3)
void gemm_main(const float* __restrict__ Q, const float* __restrict__ X,
               const unsigned short* __restrict__ Wt, const float* __restrict__ bcat,
               float* __restrict__ out, int M) {
  __shared__ __align__(16) unsigned short As[128 * 32];  // 8 KB
  __shared__ __align__(16) unsigned short Bs[128 * 32];  // 8 KB

  const int nt = blockIdx.x;     // 0..5
  const int mt = blockIdx.y;
  const int mBase = mt * 128;
  const int nBase = nt * 128;
  const float* A = (nt < 2) ? X : Q;

  const int tid  = threadIdx.x;
  const int lane = tid & 63;
  const int wid  = tid >> 6;
  const int mw   = (wid >> 1) * 64;
  const int nw   = (wid & 1) * 64;
  const int lrow = lane & 15;
  const int quad = lane >> 4;

  floatx4 acc[4][4] = {};

  const float* Ab = A + (size_t)mBase * 256;
  const unsigned short* Bb = Wt + (size_t)nBase * 256;

  for (int s = 0; s < 8; ++s) {
    const int k0 = s * 32;
    __syncthreads();
    // ---- async B stage: 128x32 bf16 = 512 x 16B chunks, 2 per thread ----
#pragma unroll
    for (int j = 0; j < 2; ++j) {
      int ch = j * 256 + tid;
      int r = ch >> 2, kc = ch & 3;
      const unsigned short* g = Bb + (size_t)r * 256 + k0 + kc * 8;
      unsigned ldsoff = (unsigned)((j * 256 + (tid & ~63)) * 16);  // wave-uniform
      __builtin_amdgcn_global_load_lds((const AS1 void*)g,
                                       (AS3 void*)(((char*)Bs) + ldsoff), 16, 0, 0);
    }
    // ---- A stage: 128x32 fp32 -> bf16: 1024 x (4 float) chunks, 4/thread ----
    float4 va[4];
#pragma unroll
    for (int i = 0; i < 4; ++i) {
      int id = i * 256 + tid;
      int r = id >> 3, kc = id & 7;
      va[i] = *(const float4*)(Ab + (size_t)r * 256 + k0 + kc * 4);
    }
#pragma unroll
    for (int i = 0; i < 4; ++i) {
      int id = i * 256 + tid;
      uint2 pk;
      pk.x = ((unsigned)f2b_rne(va[i].y) << 16) | f2b_rne(va[i].x);
      pk.y = ((unsigned)f2b_rne(va[i].w) << 16) | f2b_rne(va[i].z);
      *(uint2*)(&As[id * 4]) = pk;
    }
    __syncthreads();
    // ---- compute: wave does 64x64 = 4x4 of 16x16x32 ----
    short8 af[4], bf[4];
#pragma unroll
    for (int mi = 0; mi < 4; ++mi)
      af[mi] = *(const short8*)(&As[(mw + mi * 16 + lrow) * 32 + quad * 8]);
#pragma unroll
    for (int ni = 0; ni < 4; ++ni)
      bf[ni] = *(const short8*)(&Bs[(nw + ni * 16 + lrow) * 32 + quad * 8]);
#pragma unroll
    for (int mi = 0; mi < 4; ++mi)
#pragma unroll
      for (int ni = 0; ni < 4; ++ni)
        acc[mi][ni] = __builtin_amdgcn_mfma_f32_16x16x32_bf16(af[mi], bf[ni], acc[mi][ni], 0, 0, 0);
  }

  // ---- epilogue: bias + store. C/D layout: col=lane&15, row=quad*4+reg ----
  const int seg  = nt >> 1;   // 0=value, 1=curr_off, 2=temp_off
  const int half = nt & 1;
  float* Oseg = out + (size_t)seg * ((size_t)M * 256) + (size_t)half * 128;
#pragma unroll
  for (int ni = 0; ni < 4; ++ni) {
    float bias = bcat[nBase + nw + ni * 16 + lrow];
#pragma unroll
    for (int mi = 0; mi < 4; ++mi) {
#pragma unroll
      for (int r = 0; r < 4; ++r) {
        int row = mBase + mw + mi * 16 + quad * 4 + r;
        int col = nw + ni * 16 + lrow;
        Oseg[(size_t)row * 256 + col] = acc[mi][ni][r] + bias;
      }
    }
  }
}

// ---------------------------------------------------------------------------
// aw GEMM + fused softmax: 64 rows x 256 cols per block (cols 0..127 caw,
// 128..255 taw). Logits -> LDS -> per-(row,head) softmax over 32 -> out.
// ---------------------------------------------------------------------------
__global__ __launch_bounds__(256, 2)
void gemm_aw(const float* __restrict__ Q, const unsigned short* __restrict__ Wt,
             const float* __restrict__ bcat, float* __restrict__ awc,
             float* __restrict__ awt, int M) {
  __shared__ __align__(16) float Ls[64 * 256];            // 64 KB (union)
  unsigned short* As = (unsigned short*)Ls;               // [64*32]  bytes [0,4096)
  unsigned short* Bs = ((unsigned short*)Ls) + 2048;      // [256*32] bytes [4096,20480)

  const int mt = blockIdx.x;
  const int mBase = mt * 64;

  const int tid  = threadIdx.x;
  const int lane = tid & 63;
  const int wid  = tid >> 6;
  const int nw   = wid * 64;        // wave's 64-col span of the 256
  const int lrow = lane & 15;
  const int quad = lane >> 4;

  floatx4 acc[4][4] = {};

  const float* Ab = Q + (size_t)mBase * 256;
  const unsigned short* Bb = Wt + (size_t)768 * 256;

  for (int s = 0; s < 8; ++s) {
    const int k0 = s * 32;
    __syncthreads();
    // ---- B stage: 256x32 bf16 = 1024 x 16B chunks, 4/thread ----
#pragma unroll
    for (int j = 0; j < 4; ++j) {
      int ch = j * 256 + tid;
      int r = ch >> 2, kc = ch & 3;
      const unsigned short* g = Bb + (size_t)r * 256 + k0 + kc * 8;
      unsigned ldsoff = 4096u + (unsigned)((j * 256 + (tid & ~63)) * 16);
      __builtin_amdgcn_global_load_lds((const AS1 void*)g,
                                       (AS3 void*)(((char*)Ls) + ldsoff), 16, 0, 0);
    }
    // ---- A stage: 64x32 fp32 -> bf16: 512 chunks, 2/thread ----
    float4 va[2];
#pragma unroll
    for (int i = 0; i < 2; ++i) {
      int id = i * 256 + tid;
      int r = id >> 3, kc = id & 7;
      va[i] = *(const float4*)(Ab + (size_t)r * 256 + k0 + kc * 4);
    }
#pragma unroll
    for (int i = 0; i < 2; ++i) {
      int id = i * 256 + tid;
      uint2 pk;
      pk.x = ((unsigned)f2b_rne(va[i].y) << 16) | f2b_rne(va[i].x);
      pk.y = ((unsigned)f2b_rne(va[i].w) << 16) | f2b_rne(va[i].z);
      *(uint2*)(&As[id * 4]) = pk;
    }
    __syncthreads();
    // ---- compute: wave does 64(m) x 64(n) ----
    short8 af[4], bf[4];
#pragma unroll
    for (int mi = 0; mi < 4; ++mi)
      af[mi] = *(const short8*)(&As[(mi * 16 + lrow) * 32 + quad * 8]);
#pragma unroll
    for (int ni = 0; ni < 4; ++ni)
      bf[ni] = *(const short8*)(&Bs[(nw + ni * 16 + lrow) * 32 + quad * 8]);
#pragma unroll
    for (int mi = 0; mi < 4; ++mi)
#pragma unroll
      for (int ni = 0; ni < 4; ++ni)
        acc[mi][ni] = __builtin_amdgcn_mfma_f32_16x16x32_bf16(af[mi], bf[ni], acc[mi][ni], 0, 0, 0);
  }

  __syncthreads();  // staging region aliases the logit buffer — drain reads

  // ---- logits (+bias) -> LDS ----
#pragma unroll
  for (int ni = 0; ni < 4; ++ni) {
    float bias = bcat[768 + nw + ni * 16 + lrow];
#pragma unroll
    for (int mi = 0; mi < 4; ++mi) {
#pragma unroll
      for (int r = 0; r < 4; ++r) {
        int row = mi * 16 + quad * 4 + r;
        int col = nw + ni * 16 + lrow;
        Ls[row * 256 + col] = acc[mi][ni][r] + bias;
      }
    }
  }
  __syncthreads();

  // ---- softmax over 32 per (row, head): 64*8 = 512 pairs, 2/thread ----
#pragma unroll
  for (int i = 0; i < 2; ++i) {
    int p = i * 256 + tid;
    int row = p >> 3, h = p & 7;
    const float* lc = &Ls[row * 256 + h * 16];
    const float* lt = &Ls[row * 256 + 128 + h * 16];
    float v[32];
#pragma unroll
    for (int j = 0; j < 16; ++j) { v[j] = lc[j]; v[16 + j] = lt[j]; }
    float mx = v[0];
#pragma unroll
    for (int j = 1; j < 32; ++j) mx = fmaxf(mx, v[j]);
    float ssum = 0.f;
#pragma unroll
    for (int j = 0; j < 32; ++j) { v[j] = __expf(v[j] - mx); ssum += v[j]; }
    float inv = 1.0f / ssum;
    float* oc = awc + (size_t)(mBase + row) * 128 + h * 16;
    float* ot = awt + (size_t)(mBase + row) * 128 + h * 16;
#pragma unroll
    for (int g = 0; g < 4; ++g) {
      float4 c4 = make_float4(v[g*4+0]*inv, v[g*4+1]*inv, v[g*4+2]*inv, v[g*4+3]*inv);
      float4 t4 = make_float4(v[16+g*4+0]*inv, v[16+g*4+1]*inv, v[16+g*4+2]*inv, v[16+g*4+3]*inv);
      *(float4*)(oc + g * 4) = c4;
      *(float4*)(ot + g * 4) = t4;
    }
  }
}

// ---------------------------------------------------------------------------
extern "C" void kernel_launch(void* const* d_in, const int* in_sizes, int n_in,
                              void* d_out, int out_size, void* d_ws, size_t ws_size,
                              hipStream_t stream) {
  const float* Q    = (const float*)d_in[0];
  const float* Xf   = (const float*)d_in[1];
  const float* Wv   = (const float*)d_in[2];
  const float* bv   = (const float*)d_in[3];
  const float* Wso  = (const float*)d_in[4];
  const float* bso  = (const float*)d_in[5];
  const float* Waw  = (const float*)d_in[6];
  const float* baw  = (const float*)d_in[7];
  const float* Wtso = (const float*)d_in[8];
  const float* btso = (const float*)d_in[9];
  const float* Wtaw = (const float*)d_in[10];
  const float* btaw = (const float*)d_in[11];
  float* out = (float*)d_out;

  unsigned short* Wt = (unsigned short*)d_ws;               // 512 KB
  float* bcat = (float*)((char*)d_ws + 1024 * 256 * 2);     // 4 KB

  int M = in_sizes[0] / 256;  // 97920

  prep_weights<<<1024, 256, 0, stream>>>(Wv, bv, Wso, bso, Waw, baw,
                                         Wtso, btso, Wtaw, btaw, Wt, bcat);

  dim3 g1(6, M / 128);  // n-tile fastest: all 6 n-tiles of an m-row co-temporal
  gemm_main<<<g1, 256, 0, stream>>>(Q, Xf, Wt, bcat, out, M);

  float* awc = out + (size_t)3 * M * 256;
  float* awt = awc + (size_t)M * 128;
  gemm_aw<<<M / 64, 256, 0, stream>>>(Q, Wt, bcat, awc, awt, M);
}